// Round 3
// baseline (301.248 us; speedup 1.0000x reference)
//
#include <hip/hip_runtime.h>

#define D 128
#define SCAN_B 256
#define NT 32            // nodes per fused_ag block
#define HPAD 132         // padded LDS row (floats) — breaks stride-128 bank alias

typedef short bf16x8 __attribute__((ext_vector_type(8)));
typedef float f32x4 __attribute__((ext_vector_type(4)));

static __device__ __forceinline__ unsigned short f2bf(float f) {
  union { float f; unsigned u; } v; v.f = f;
  return (unsigned short)((v.u + 0x7FFF + ((v.u >> 16) & 1)) >> 16);   // RNE
}
static __device__ __forceinline__ float bf2f(unsigned short h) {
  union { unsigned u; float f; } v; v.u = ((unsigned)h) << 16;
  return v.f;
}
static __device__ __forceinline__ float bflo(unsigned u) {
  union { unsigned u; float f; } v; v.u = u << 16; return v.f;
}
static __device__ __forceinline__ float bfhi(unsigned u) {
  union { unsigned u; float f; } v; v.u = u & 0xFFFF0000u; return v.f;
}

// ---------------------------------------------------------------------------
// prep_kernel: blocks [0,16)   : Wself/Wfwd -> bf16 MFMA-B-swizzled Wb
//              blocks [16,+rB) : rel_out = rel @ Wr^T (2 rel rows per block)
//              rest            : zero offs (int4 stores)
// ---------------------------------------------------------------------------
__global__ __launch_bounds__(256) void prep_kernel(
    const float* __restrict__ Wself, const float* __restrict__ Wfwd,
    const float* __restrict__ rel, const float* __restrict__ Wr,
    unsigned short* __restrict__ Wb, float* __restrict__ rel_out,
    int* __restrict__ offs, int nR, int nN, int relBlocks) {
  const int tid = threadIdx.x;
  if ((int)blockIdx.x < 16) {
    // Wb[frag*512 + lane*8 + j]: frag=((mat*8+ct)*4+kt); lane(q=lane>>4,r=lane&15)
    // holds W[ct*16+r][kt*32+q*8+j].  mat0=Wself, mat1=Wfwd.
    const int g = blockIdx.x * 256 + tid;     // 0..4095
    const int frag = g >> 6, lane = g & 63;
    const int mat = frag >> 5, ct = (frag >> 2) & 7, kt = frag & 3;
    const int q = lane >> 4, r = lane & 15;
    const float* W = mat ? Wfwd : Wself;
    const float* src = W + (ct * 16 + r) * D + kt * 32 + q * 8;
    unsigned short* dstp = Wb + frag * 512 + lane * 8;
    #pragma unroll
    for (int j = 0; j < 8; ++j) dstp[j] = f2bf(src[j]);
  } else if ((int)blockIdx.x < 16 + relBlocks) {
    __shared__ float row[2][D];
    const int half = tid >> 7;                 // 0/1: which rel row
    const int c = tid & 127;
    const int rr = ((int)blockIdx.x - 16) * 2 + half;
    const int r2 = (rr < nR) ? rr : nR - 1;
    row[half][c] = rel[r2 * D + c];
    __syncthreads();
    const float4* xr4 = (const float4*)row[half];
    const float4* Wr4 = (const float4*)(Wr + c * D);
    float ar = 0.f;
    #pragma unroll 8
    for (int k4 = 0; k4 < 32; ++k4) {
      const float4 xv = xr4[k4];
      const float4 wr = Wr4[k4];
      ar += xv.x * wr.x + xv.y * wr.y + xv.z * wr.z + xv.w * wr.w;
    }
    if (rr < nR) rel_out[rr * D + c] = ar;
  } else {
    const int i = ((int)blockIdx.x - 16 - relBlocks) * 256 + tid;  // int4 index
    const int e0 = i * 4;
    if (e0 < nN) {
      if (e0 + 3 < nN) ((int4*)offs)[i] = make_int4(0, 0, 0, 0);
      else { for (int k = e0; k < nN; ++k) offs[k] = 0; }
    }
  }
}

// ---------------------------------------------------------------------------
// xb_hist: blocks [0,xbBlocks): xb = bf16(x)  (8 elems/thread, 16B stores)
//          rest               : dst histogram (atomics hidden behind BW work)
// ---------------------------------------------------------------------------
__global__ __launch_bounds__(256) void xb_hist(
    const float* __restrict__ x, unsigned short* __restrict__ xb,
    const int* __restrict__ dst, int* __restrict__ offs,
    int nElems, int nE, int xbBlocks) {
  if ((int)blockIdx.x < xbBlocks) {
    const int i = ((int)blockIdx.x * 256 + (int)threadIdx.x) * 8;
    if (i + 7 < nElems) {
      const float4 u0 = *(const float4*)(x + i);
      const float4 u1 = *(const float4*)(x + i + 4);
      const unsigned p0 = (unsigned)f2bf(u0.x) | ((unsigned)f2bf(u0.y) << 16);
      const unsigned p1 = (unsigned)f2bf(u0.z) | ((unsigned)f2bf(u0.w) << 16);
      const unsigned p2 = (unsigned)f2bf(u1.x) | ((unsigned)f2bf(u1.y) << 16);
      const unsigned p3 = (unsigned)f2bf(u1.z) | ((unsigned)f2bf(u1.w) << 16);
      *(int4*)(xb + i) = make_int4((int)p0, (int)p1, (int)p2, (int)p3);
    } else {
      for (int k = i; k < nElems; ++k) xb[k] = f2bf(x[k]);
    }
  } else {
    const int i0 = (((int)blockIdx.x - xbBlocks) * 256 + (int)threadIdx.x) * 4;
    if (i0 + 3 < nE) {
      const int4 d4 = *(const int4*)(dst + i0);
      atomicAdd(&offs[d4.x], 1); atomicAdd(&offs[d4.y], 1);
      atomicAdd(&offs[d4.z], 1); atomicAdd(&offs[d4.w], 1);
    } else {
      for (int e = i0; e < nE && e < i0 + 4; ++e) atomicAdd(&offs[dst[e]], 1);
    }
  }
}

// ---------------------------------------------------------------------------
// exclusive scan over offs (3 small kernels)
// ---------------------------------------------------------------------------
__global__ __launch_bounds__(SCAN_B) void scan_pass1(
    const int* __restrict__ deg, int* __restrict__ bsum, int n) {
  __shared__ int sd[SCAN_B];
  const int i = blockIdx.x * SCAN_B + threadIdx.x;
  sd[threadIdx.x] = (i < n) ? deg[i] : 0;
  __syncthreads();
  for (int s = SCAN_B / 2; s > 0; s >>= 1) {
    if (threadIdx.x < s) sd[threadIdx.x] += sd[threadIdx.x + s];
    __syncthreads();
  }
  if (threadIdx.x == 0) bsum[blockIdx.x] = sd[0];
}

__global__ __launch_bounds__(1024) void scan_pass2(int* __restrict__ bsum, int nb) {
  __shared__ int sd[1024];
  const int t = threadIdx.x;
  const int v = (t < nb) ? bsum[t] : 0;
  sd[t] = v;
  __syncthreads();
  for (int off = 1; off < 1024; off <<= 1) {
    const int add = (t >= off) ? sd[t - off] : 0;
    __syncthreads();
    sd[t] += add;
    __syncthreads();
  }
  if (t < nb) bsum[t] = sd[t] - v;   // exclusive
}

__global__ __launch_bounds__(SCAN_B) void scan_pass3(
    int* __restrict__ deg_offs, const int* __restrict__ bsum, int n) {
  __shared__ int sd[SCAN_B];
  const int i = blockIdx.x * SCAN_B + threadIdx.x;
  const int t = threadIdx.x;
  const int v = (i < n) ? deg_offs[i] : 0;
  sd[t] = v;
  __syncthreads();
  for (int off = 1; off < SCAN_B; off <<= 1) {
    const int add = (t >= off) ? sd[t - off] : 0;
    __syncthreads();
    sd[t] += add;
    __syncthreads();
  }
  if (i < n) deg_offs[i] = sd[t] - v + bsum[blockIdx.x];   // exclusive global
}

// ---------------------------------------------------------------------------
// fill: CSR-ordered PACKED metadata. meta[p] = {src | et<<20, bits(ew)}.
// After this, offs[n] == end of bucket n (cursor advanced to end).
// ---------------------------------------------------------------------------
__global__ void fill_kernel(const int* __restrict__ src, const int* __restrict__ dstv,
                            const int* __restrict__ et, const float* __restrict__ ew,
                            int* __restrict__ cursor, uint2* __restrict__ meta, int nE) {
  const int e = blockIdx.x * blockDim.x + threadIdx.x;
  if (e < nE) {
    const int p = atomicAdd(&cursor[dstv[e]], 1);
    meta[p] = make_uint2((unsigned)src[e] | ((unsigned)et[e] << 20),
                         __float_as_uint(ew[e]));
  }
}

// ---------------------------------------------------------------------------
// fused_ag v2: aggregate-then-project, h never touches HBM.
//  32-node tile, 16.9KB LDS -> 8 blocks/CU (32 waves/CU) under
//  __launch_bounds__(256,8) [VGPR<=64].
//  Agg: block's CSR edge range split EVENLY over 16 groups (position-
//  balanced); each group walks node boundaries with register-cached
//  nextEnd, accumulates in registers, flushes to padded hsm via rare
//  ds_add_f32 atomics. Depth-2 static prefetch of xb/rel gathers.
//  GEMM: 4 waves: wave = (row-half, col-half). acc = x@Ws + hi@Wf + lo@Wf.
//  Direct scalar stores (4 x 64B segments per instr), no stash barrier.
// ---------------------------------------------------------------------------
__global__ __launch_bounds__(256, 8) void fused_ag(
    const uint4* __restrict__ xb4, const float4* __restrict__ rel4,
    const uint2* __restrict__ meta, const int* __restrict__ offs,
    const unsigned short* __restrict__ Wb, const float* __restrict__ bias,
    const unsigned short* __restrict__ xb, float* __restrict__ out,
    int nN, int useGlobalH, const float* __restrict__ hg) {
  __shared__ float hsm[NT][HPAD];          // 16.9 KB
  __shared__ int bndv[NT + 1];
  const int tid = threadIdx.x;
  const int g0 = blockIdx.x * NT;

  // zero hsm (flat float4 writes)
  {
    float4* hz = (float4*)&hsm[0][0];
    for (int i = tid; i < NT * HPAD / 4; i += 256)
      hz[i] = make_float4(0.f, 0.f, 0.f, 0.f);
  }
  if (tid <= NT) {
    int v;
    if (tid == 0) v = (g0 == 0) ? 0 : offs[g0 - 1];
    else { int idx = g0 + tid - 1; if (idx > nN - 1) idx = nN - 1; v = offs[idx]; }
    bndv[tid] = v;
  }
  __syncthreads();

  if (!useGlobalH) {
    const int l16 = tid & 15;
    const int g = tid >> 4;                          // group 0..15
    const int start = bndv[0], end = bndv[NT];
    const int Q = ((end - start) + 15) >> 4;         // even position split
    int p0 = start + g * Q;
    int p1 = p0 + Q; if (p1 > end) p1 = end;
    if (p0 < p1) {
      // init cur = largest node index with bndv[cur] <= p0 (binary search)
      int cur = 0;
      #pragma unroll
      for (int s = 16; s > 0; s >>= 1)
        if (cur + s <= NT - 1 && bndv[cur + s] <= p0) cur += s;
      int nextEnd = bndv[cur + 1];
      float acc[8] = {0.f, 0.f, 0.f, 0.f, 0.f, 0.f, 0.f, 0.f};

      for (int pb = p0; pb < p1; pb += 16) {
        const int m = (p1 - pb < 16) ? (p1 - pb) : 16;
        uint2 mv = make_uint2(0u, 0u);
        if (l16 < m) mv = meta[pb + l16];
        for (int jb = 0; jb < m; jb += 2) {
          // ---- issue both edges' gathers up front (depth-2 MLP) ----
          uint4 av0, av1; float4 r0a, r1a, r0b, r1b; float w0, w1;
          {
            const int j = jb;
            const unsigned pk = (unsigned)__shfl((int)mv.x, j, 16);
            w0 = __uint_as_float(__shfl((int)mv.y, j, 16));
            const int s = (int)(pk & 0xFFFFFu);
            const int t = (int)(pk >> 20);
            av0 = xb4[(size_t)s * 16 + l16];
            r0a = rel4[(size_t)t * 32 + l16 * 2];
            r1a = rel4[(size_t)t * 32 + l16 * 2 + 1];
          }
          {
            int j = jb + 1; if (j >= m) j = m - 1;   // dup of last: harmless
            const unsigned pk = (unsigned)__shfl((int)mv.x, j, 16);
            w1 = __uint_as_float(__shfl((int)mv.y, j, 16));
            const int s = (int)(pk & 0xFFFFFu);
            const int t = (int)(pk >> 20);
            av1 = xb4[(size_t)s * 16 + l16];
            r0b = rel4[(size_t)t * 32 + l16 * 2];
            r1b = rel4[(size_t)t * 32 + l16 * 2 + 1];
          }
          // ---- consume edge jb ----
          {
            const int p = pb + jb;
            while (p >= nextEnd) {
              float* hrow = hsm[cur];
              #pragma unroll
              for (int i = 0; i < 8; ++i) {
                if (acc[i] != 0.f) atomicAdd(&hrow[l16 * 8 + i], acc[i]);
                acc[i] = 0.f;
              }
              ++cur; nextEnd = bndv[cur + 1];
            }
            acc[0] += w0 * (bflo(av0.x) - r0a.x);
            acc[1] += w0 * (bfhi(av0.x) - r0a.y);
            acc[2] += w0 * (bflo(av0.y) - r0a.z);
            acc[3] += w0 * (bfhi(av0.y) - r0a.w);
            acc[4] += w0 * (bflo(av0.z) - r1a.x);
            acc[5] += w0 * (bfhi(av0.z) - r1a.y);
            acc[6] += w0 * (bflo(av0.w) - r1a.z);
            acc[7] += w0 * (bfhi(av0.w) - r1a.w);
          }
          // ---- consume edge jb+1 (if real) ----
          if (jb + 1 < m) {
            const int p = pb + jb + 1;
            while (p >= nextEnd) {
              float* hrow = hsm[cur];
              #pragma unroll
              for (int i = 0; i < 8; ++i) {
                if (acc[i] != 0.f) atomicAdd(&hrow[l16 * 8 + i], acc[i]);
                acc[i] = 0.f;
              }
              ++cur; nextEnd = bndv[cur + 1];
            }
            acc[0] += w1 * (bflo(av1.x) - r0b.x);
            acc[1] += w1 * (bfhi(av1.x) - r0b.y);
            acc[2] += w1 * (bflo(av1.y) - r0b.z);
            acc[3] += w1 * (bfhi(av1.y) - r0b.w);
            acc[4] += w1 * (bflo(av1.z) - r1b.x);
            acc[5] += w1 * (bfhi(av1.z) - r1b.y);
            acc[6] += w1 * (bflo(av1.w) - r1b.z);
            acc[7] += w1 * (bfhi(av1.w) - r1b.w);
          }
        }
      }
      // final flush
      {
        float* hrow = hsm[cur];
        #pragma unroll
        for (int i = 0; i < 8; ++i)
          if (acc[i] != 0.f) atomicAdd(&hrow[l16 * 8 + i], acc[i]);
      }
    }
  } else if (hg) {
    for (int idx = tid; idx < NT * 32; idx += 256) {
      const int rr = idx >> 5, cc = (idx & 31) * 4;
      const int n = g0 + rr;
      float4 v = make_float4(0.f, 0.f, 0.f, 0.f);
      if (n < nN) v = *(const float4*)(hg + (size_t)n * D + cc);
      *(float4*)&hsm[rr][cc] = v;
    }
  }
  __syncthreads();

  // ---- GEMM phase: wave w = (row-half w>>1, col-half w&1) -------------
  const int w = tid >> 6, lane = tid & 63;
  const int q = lane >> 4, r = lane & 15;
  const int rowbase = (w >> 1) * 16;
  const int ch = w & 1;
  const int lr = rowbase + r;
  int grow = g0 + lr; if (grow >= nN) grow = nN - 1;

  f32x4 acc[4];
  #pragma unroll
  for (int c2 = 0; c2 < 4; ++c2) acc[c2] = (f32x4)0.f;

  #pragma unroll
  for (int kt = 0; kt < 4; ++kt) {
    const bf16x8 xa = *(const bf16x8*)(xb + (size_t)grow * D + kt * 32 + q * 8);
    const float* hp = &hsm[lr][kt * 32 + q * 8];
    const float4 h0 = *(const float4*)hp;
    const float4 h1 = *(const float4*)(hp + 4);
    const float hv[8] = {h0.x, h0.y, h0.z, h0.w, h1.x, h1.y, h1.z, h1.w};
    bf16x8 hi, lo;
    #pragma unroll
    for (int j = 0; j < 8; ++j) {
      const unsigned short hb = f2bf(hv[j]);
      hi[j] = (short)hb;
      lo[j] = (short)f2bf(hv[j] - bf2f(hb));
    }
    #pragma unroll
    for (int c2 = 0; c2 < 4; ++c2) {
      const int ct = ch * 4 + c2;
      const bf16x8 bS = *(const bf16x8*)(Wb + ((0 * 8 + ct) * 4 + kt) * 512 + lane * 8);
      const bf16x8 bF = *(const bf16x8*)(Wb + ((1 * 8 + ct) * 4 + kt) * 512 + lane * 8);
      acc[c2] = __builtin_amdgcn_mfma_f32_16x16x32_bf16(xa, bS, acc[c2], 0, 0, 0);
      acc[c2] = __builtin_amdgcn_mfma_f32_16x16x32_bf16(hi, bF, acc[c2], 0, 0, 0);
      acc[c2] = __builtin_amdgcn_mfma_f32_16x16x32_bf16(lo, bF, acc[c2], 0, 0, 0);
    }
  }

  // direct stores: C/D layout col=ct*16+r, row=rowbase+q*4+reg
  #pragma unroll
  for (int c2 = 0; c2 < 4; ++c2) {
    const int col = ch * 64 + c2 * 16 + r;
    const float bv = bias[col];
    #pragma unroll
    for (int reg = 0; reg < 4; ++reg) {
      const int row = g0 + rowbase + q * 4 + reg;
      if (row < nN) out[(size_t)row * D + col] = acc[c2][reg] + bv;
    }
  }
}

// ---------------------------------------------------------------------------
// Fallbacks (never taken at harness sizes)
// ---------------------------------------------------------------------------
__global__ __launch_bounds__(256) void hzero(float* __restrict__ h, int n4) {
  const int i = blockIdx.x * 256 + threadIdx.x;
  if (i < n4) ((int4*)h)[i] = make_int4(0, 0, 0, 0);
}

__global__ __launch_bounds__(256) void hscatter(
    const uint4* __restrict__ xb4, const float* __restrict__ rel,
    const int* __restrict__ ei, const int* __restrict__ etype,
    const float* __restrict__ ew, float* __restrict__ h, int nE) {
  const int e = blockIdx.x * 16 + ((int)threadIdx.x >> 4);
  if (e >= nE) return;
  const int l = threadIdx.x & 15;
  const int s = ei[e], d = ei[nE + e], t = etype[e];
  const float wv = ew[e];
  const uint4 a = xb4[(size_t)s * 16 + l];
  const float4 r0 = ((const float4*)(rel + (size_t)t * D))[l * 2];
  const float4 r1 = ((const float4*)(rel + (size_t)t * D))[l * 2 + 1];
  float* o = h + (size_t)d * D + l * 8;
  atomicAdd(o + 0, wv * (bflo(a.x) - r0.x));
  atomicAdd(o + 1, wv * (bfhi(a.x) - r0.y));
  atomicAdd(o + 2, wv * (bflo(a.y) - r0.z));
  atomicAdd(o + 3, wv * (bfhi(a.y) - r0.w));
  atomicAdd(o + 4, wv * (bflo(a.z) - r1.x));
  atomicAdd(o + 5, wv * (bfhi(a.z) - r1.y));
  atomicAdd(o + 6, wv * (bflo(a.w) - r1.z));
  atomicAdd(o + 7, wv * (bfhi(a.w) - r1.w));
}

// ultra-safe last resort: fp32 per-edge scatter straight into out
__global__ __launch_bounds__(256) void edge_scatter_f32(
    const float* __restrict__ x, const float* __restrict__ rel,
    const float* __restrict__ Wfwd,
    const int* __restrict__ ei, const int* __restrict__ etype,
    const float* __restrict__ ew, float* __restrict__ out, int nE) {
  __shared__ float msg[2][D];
  const int half = (int)threadIdx.x >> 7;     // 2 edges / block
  const int c = threadIdx.x & 127;
  const int e = blockIdx.x * 2 + half;
  if (e >= nE) return;
  const int s = ei[e], d = ei[nE + e], t = etype[e];
  msg[half][c] = x[(size_t)s * D + c] - rel[(size_t)t * D + c];
  __syncthreads();
  float a = 0.f;
  #pragma unroll 8
  for (int k = 0; k < D; ++k) a += msg[half][k] * Wfwd[c * D + k];
  atomicAdd(&out[(size_t)d * D + c], ew[e] * a);
}

// ---------------------------------------------------------------------------
extern "C" void kernel_launch(void* const* d_in, const int* in_sizes, int n_in,
                              void* d_out, int out_size, void* d_ws, size_t ws_size,
                              hipStream_t stream) {
  const float* x      = (const float*)d_in[0];
  const int*   ei     = (const int*)d_in[1];
  const int*   etype  = (const int*)d_in[2];
  const float* rel    = (const float*)d_in[3];
  const float* ew     = (const float*)d_in[4];
  const float* Wself  = (const float*)d_in[5];
  const float* Wfwd   = (const float*)d_in[6];
  const float* Wrel   = (const float*)d_in[7];
  const float* bias   = (const float*)d_in[8];

  const int nN = in_sizes[0] / D;       // 100000
  const int nE = in_sizes[2];           // 625000
  const int nR = in_sizes[3] / D;       // 200

  float* out     = (float*)d_out;
  float* rel_out = (float*)d_out + (size_t)nN * D;

  // workspace carve-up (256B-aligned)
  char* w = (char*)d_ws;
  size_t off = 0;
  auto carve = [&](size_t bytes) {
    char* p = w + off;
    off = (off + bytes + 255) & ~(size_t)255;
    return p;
  };
  unsigned short* xb  = (unsigned short*)carve((size_t)nN * D * sizeof(unsigned short));
  unsigned short* Wb  = (unsigned short*)carve(2 * 8 * 4 * 512 * sizeof(unsigned short));
  int*   offs = (int*)carve((size_t)nN * sizeof(int));
  uint2* meta = (uint2*)carve((size_t)nE * sizeof(uint2));
  int*   bsum = (int*)carve(1024 * sizeof(int));
  const size_t need = off;

  const int* dst = ei + nE;
  const int nb = (nN + SCAN_B - 1) / SCAN_B;
  const int relBlocks  = (nR + 1) / 2;
  const int zeroBlocks = (nN + 1023) / 1024;
  const int xbBlocks   = (int)(((size_t)nN * D + 2047) / 2048);
  const int histBlocks = (nE + 1023) / 1024;
  const int aggBlocks  = (nN + NT - 1) / NT;

  const bool csr_ok = (need <= ws_size) && (nb <= 1024) &&
                      (nN < (1 << 20)) && (nR <= 4096);
  const size_t hBytes = (size_t)nN * D * sizeof(float);
  const bool h_ok = ((size_t)nN * D * sizeof(unsigned short) + 256 + hBytes) <= ws_size;

  // Wb prep + rel_out GEMV + zero offs (one dispatch)
  prep_kernel<<<16 + relBlocks + zeroBlocks, 256, 0, stream>>>(
      Wself, Wfwd, rel, Wrel, Wb, rel_out, offs, nR, nN, relBlocks);

  if (csr_ok) {
    // xb = bf16(x) + dst histogram, co-scheduled (atomics hidden behind BW)
    xb_hist<<<xbBlocks + histBlocks, 256, 0, stream>>>(
        x, xb, dst, offs, nN * D, nE, xbBlocks);
    scan_pass1<<<nb, SCAN_B, 0, stream>>>(offs, bsum, nN);
    scan_pass2<<<1, 1024, 0, stream>>>(bsum, nb);
    scan_pass3<<<nb, SCAN_B, 0, stream>>>(offs, bsum, nN);
    fill_kernel<<<(nE + 255) / 256, 256, 0, stream>>>(ei, dst, etype, ew, offs, meta, nE);
    fused_ag<<<aggBlocks, 256, 0, stream>>>(
        (const uint4*)xb, (const float4*)rel, meta, offs, Wb, bias, xb, out,
        nN, 0, (const float*)0);
  } else if (h_ok) {
    // h in global via atomics, then the same fused GEMM
    char* w2 = (char*)d_ws;
    unsigned short* xb2 = (unsigned short*)w2;
    float* h = (float*)(w2 + (((size_t)nN * D * sizeof(unsigned short) + 255) & ~(size_t)255));
    xb_hist<<<xbBlocks, 256, 0, stream>>>(x, xb2, dst, (int*)0, nN * D, 0, xbBlocks);
    const int n4 = (nN * D) / 4;
    hzero<<<(n4 + 255) / 256, 256, 0, stream>>>(h, n4);
    hscatter<<<(nE + 15) / 16, 256, 0, stream>>>(
        (const uint4*)xb2, rel, ei, etype, ew, h, nE);
    fused_ag<<<aggBlocks, 256, 0, stream>>>(
        (const uint4*)xb2, (const float4*)rel, (const uint2*)0, (const int*)0,
        Wb, bias, xb2, out, nN, 1, h);
  } else {
    // last resort: fused self-GEMM with h=0 (hg==null -> hsm stays zero),
    // then fp32 per-edge atomic scatter of the message term
    unsigned short* xb2 = (unsigned short*)d_ws;   // only xb needed
    xb_hist<<<xbBlocks, 256, 0, stream>>>(x, xb2, dst, (int*)0, nN * D, 0, xbBlocks);
    fused_ag<<<aggBlocks, 256, 0, stream>>>(
        (const uint4*)xb2, (const float4*)rel, (const uint2*)0, (const int*)0,
        Wb, bias, xb2, out, nN, 1, (const float*)0);
    edge_scatter_f32<<<(nE + 1) / 2, 256, 0, stream>>>(
        x, rel, Wfwd, ei, etype, ew, out, nE);
  }
}

// Round 4
// 295.019 us; speedup vs baseline: 1.0211x; 1.0211x over previous
//
#include <hip/hip_runtime.h>

#define D 128
#define SCAN_B 256
#define NT 32            // nodes per fused_ag block
#define HPAD 132         // padded LDS row (floats) — breaks stride-128 bank alias

typedef short bf16x8 __attribute__((ext_vector_type(8)));
typedef float f32x4 __attribute__((ext_vector_type(4)));

static __device__ __forceinline__ unsigned short f2bf(float f) {
  union { float f; unsigned u; } v; v.f = f;
  return (unsigned short)((v.u + 0x7FFF + ((v.u >> 16) & 1)) >> 16);   // RNE
}
static __device__ __forceinline__ float bf2f(unsigned short h) {
  union { unsigned u; float f; } v; v.u = ((unsigned)h) << 16;
  return v.f;
}
static __device__ __forceinline__ float bflo(unsigned u) {
  union { unsigned u; float f; } v; v.u = u << 16; return v.f;
}
static __device__ __forceinline__ float bfhi(unsigned u) {
  union { unsigned u; float f; } v; v.u = u & 0xFFFF0000u; return v.f;
}

// ---------------------------------------------------------------------------
// prep_kernel: blocks [0,16)            : Wself/Wfwd -> bf16 MFMA-B-swizzled Wb
//              [16, +relBlocks)         : rel_out = rel @ Wr^T (2 rows/block)
//              [.., +zeroBlocks)        : zero offs (int4 stores)
//              rest                     : xb = bf16(x)   (no deps on above)
// ---------------------------------------------------------------------------
__global__ __launch_bounds__(256) void prep_kernel(
    const float* __restrict__ Wself, const float* __restrict__ Wfwd,
    const float* __restrict__ rel, const float* __restrict__ Wr,
    const float* __restrict__ x, unsigned short* __restrict__ xb,
    unsigned short* __restrict__ Wb, float* __restrict__ rel_out,
    int* __restrict__ offs, int nR, int nN, int relBlocks, int zeroBlocks,
    int xbElems) {
  const int tid = threadIdx.x;
  const int bid = (int)blockIdx.x;
  if (bid < 16) {
    // Wb[frag*512 + lane*8 + j]: frag=((mat*8+ct)*4+kt); lane(q=lane>>4,r=lane&15)
    // holds W[ct*16+r][kt*32+q*8+j].  mat0=Wself, mat1=Wfwd.
    const int g = bid * 256 + tid;     // 0..4095
    const int frag = g >> 6, lane = g & 63;
    const int mat = frag >> 5, ct = (frag >> 2) & 7, kt = frag & 3;
    const int q = lane >> 4, r = lane & 15;
    const float* W = mat ? Wfwd : Wself;
    const float* src = W + (ct * 16 + r) * D + kt * 32 + q * 8;
    unsigned short* dstp = Wb + frag * 512 + lane * 8;
    #pragma unroll
    for (int j = 0; j < 8; ++j) dstp[j] = f2bf(src[j]);
  } else if (bid < 16 + relBlocks) {
    __shared__ float row[2][D];
    const int half = tid >> 7;                 // 0/1: which rel row
    const int c = tid & 127;
    const int rr = (bid - 16) * 2 + half;
    const int r2 = (rr < nR) ? rr : nR - 1;
    row[half][c] = rel[r2 * D + c];
    __syncthreads();
    const float4* xr4 = (const float4*)row[half];
    const float4* Wr4 = (const float4*)(Wr + c * D);
    float ar = 0.f;
    #pragma unroll 8
    for (int k4 = 0; k4 < 32; ++k4) {
      const float4 xv = xr4[k4];
      const float4 wr = Wr4[k4];
      ar += xv.x * wr.x + xv.y * wr.y + xv.z * wr.z + xv.w * wr.w;
    }
    if (rr < nR) rel_out[rr * D + c] = ar;
  } else if (bid < 16 + relBlocks + zeroBlocks) {
    const int i = (bid - 16 - relBlocks) * 256 + tid;  // int4 index
    const int e0 = i * 4;
    if (e0 < nN) {
      if (e0 + 3 < nN) ((int4*)offs)[i] = make_int4(0, 0, 0, 0);
      else { for (int k = e0; k < nN; ++k) offs[k] = 0; }
    }
  } else {
    const int i = ((bid - 16 - relBlocks - zeroBlocks) * 256 + tid) * 8;
    if (i + 7 < xbElems) {
      const float4 u0 = *(const float4*)(x + i);
      const float4 u1 = *(const float4*)(x + i + 4);
      const unsigned p0 = (unsigned)f2bf(u0.x) | ((unsigned)f2bf(u0.y) << 16);
      const unsigned p1 = (unsigned)f2bf(u0.z) | ((unsigned)f2bf(u0.w) << 16);
      const unsigned p2 = (unsigned)f2bf(u1.x) | ((unsigned)f2bf(u1.y) << 16);
      const unsigned p3 = (unsigned)f2bf(u1.z) | ((unsigned)f2bf(u1.w) << 16);
      *(int4*)(xb + i) = make_int4((int)p0, (int)p1, (int)p2, (int)p3);
    } else {
      for (int k = i; k < xbElems; ++k) xb[k] = f2bf(x[k]);
    }
  }
}

// ---------------------------------------------------------------------------
// hist_kernel: dst histogram into offs (offs zeroed by prep)
// ---------------------------------------------------------------------------
__global__ __launch_bounds__(256) void hist_kernel(
    const int* __restrict__ dst, int* __restrict__ offs, int nE) {
  const int i0 = ((int)blockIdx.x * 256 + (int)threadIdx.x) * 4;
  if (i0 + 3 < nE) {
    const int4 d4 = *(const int4*)(dst + i0);
    atomicAdd(&offs[d4.x], 1); atomicAdd(&offs[d4.y], 1);
    atomicAdd(&offs[d4.z], 1); atomicAdd(&offs[d4.w], 1);
  } else {
    for (int e = i0; e < nE && e < i0 + 4; ++e) atomicAdd(&offs[dst[e]], 1);
  }
}

// ---------------------------------------------------------------------------
// exclusive scan over offs (3 small kernels)
// ---------------------------------------------------------------------------
__global__ __launch_bounds__(SCAN_B) void scan_pass1(
    const int* __restrict__ deg, int* __restrict__ bsum, int n) {
  __shared__ int sd[SCAN_B];
  const int i = blockIdx.x * SCAN_B + threadIdx.x;
  sd[threadIdx.x] = (i < n) ? deg[i] : 0;
  __syncthreads();
  for (int s = SCAN_B / 2; s > 0; s >>= 1) {
    if (threadIdx.x < s) sd[threadIdx.x] += sd[threadIdx.x + s];
    __syncthreads();
  }
  if (threadIdx.x == 0) bsum[blockIdx.x] = sd[0];
}

__global__ __launch_bounds__(1024) void scan_pass2(int* __restrict__ bsum, int nb) {
  __shared__ int sd[1024];
  const int t = threadIdx.x;
  const int v = (t < nb) ? bsum[t] : 0;
  sd[t] = v;
  __syncthreads();
  for (int off = 1; off < 1024; off <<= 1) {
    const int add = (t >= off) ? sd[t - off] : 0;
    __syncthreads();
    sd[t] += add;
    __syncthreads();
  }
  if (t < nb) bsum[t] = sd[t] - v;   // exclusive
}

__global__ __launch_bounds__(SCAN_B) void scan_pass3(
    int* __restrict__ deg_offs, const int* __restrict__ bsum, int n) {
  __shared__ int sd[SCAN_B];
  const int i = blockIdx.x * SCAN_B + threadIdx.x;
  const int t = threadIdx.x;
  const int v = (i < n) ? deg_offs[i] : 0;
  sd[t] = v;
  __syncthreads();
  for (int off = 1; off < SCAN_B; off <<= 1) {
    const int add = (t >= off) ? sd[t - off] : 0;
    __syncthreads();
    sd[t] += add;
    __syncthreads();
  }
  if (i < n) deg_offs[i] = sd[t] - v + bsum[blockIdx.x];   // exclusive global
}

// ---------------------------------------------------------------------------
// fill: CSR-ordered PACKED metadata. meta[p] = {src | et<<20, bits(ew)}.
// After this, offs[n] == end of bucket n (cursor advanced to end).
// ---------------------------------------------------------------------------
__global__ void fill_kernel(const int* __restrict__ src, const int* __restrict__ dstv,
                            const int* __restrict__ et, const float* __restrict__ ew,
                            int* __restrict__ cursor, uint2* __restrict__ meta, int nE) {
  const int e = blockIdx.x * blockDim.x + threadIdx.x;
  if (e < nE) {
    const int p = atomicAdd(&cursor[dstv[e]], 1);
    meta[p] = make_uint2((unsigned)src[e] | ((unsigned)et[e] << 20),
                         __float_as_uint(ew[e]));
  }
}

// ---------------------------------------------------------------------------
// fused_ag v3: aggregate-then-project, h never touches HBM.
//  32-node tile, ~17KB LDS. __launch_bounds__(256,4): VGPR cap 128 so the
//  depth-2 prefetch working set (~24 regs) stays REGISTER-RESIDENT — the
//  (256,8)/VGPR=32 clamp in v2 serialized every gather (119us vs 70us).
//  Agg: block's CSR edge range split EVENLY over 16 groups (position-
//  balanced); monotone node-boundary walk with register acc, unconditional
//  LDS-atomic flush at boundaries. Depth-2 static prefetch of xb/rel.
//  GEMM: 4 waves = (row-half, col-half); acc = x@Ws + hi@Wf + lo@Wf.
// ---------------------------------------------------------------------------
__global__ __launch_bounds__(256, 4) void fused_ag(
    const uint4* __restrict__ xb4, const float4* __restrict__ rel4,
    const uint2* __restrict__ meta, const int* __restrict__ offs,
    const unsigned short* __restrict__ Wb, const float* __restrict__ bias,
    const unsigned short* __restrict__ xb, float* __restrict__ out,
    int nN, int useGlobalH, const float* __restrict__ hg) {
  __shared__ float hsm[NT][HPAD];          // ~16.9 KB
  __shared__ int bndv[NT + 1];
  const int tid = threadIdx.x;
  const int g0 = blockIdx.x * NT;

  // zero hsm (flat float4 writes)
  {
    float4* hz = (float4*)&hsm[0][0];
    for (int i = tid; i < NT * HPAD / 4; i += 256)
      hz[i] = make_float4(0.f, 0.f, 0.f, 0.f);
  }
  if (tid <= NT && !useGlobalH) {
    int v;
    if (tid == 0) v = (g0 == 0) ? 0 : offs[g0 - 1];
    else { int idx = g0 + tid - 1; if (idx > nN - 1) idx = nN - 1; v = offs[idx]; }
    bndv[tid] = v;
  }
  __syncthreads();

  if (!useGlobalH) {
    const int l16 = tid & 15;
    const int g = tid >> 4;                          // group 0..15
    const int start = bndv[0], end = bndv[NT];
    const int Q = ((end - start) + 15) >> 4;         // even position split
    int p0 = start + g * Q;
    int p1 = p0 + Q; if (p1 > end) p1 = end;
    if (p0 < p1) {
      // init cur = largest node index with bndv[cur] <= p0 (binary search)
      int cur = 0;
      #pragma unroll
      for (int s = 16; s > 0; s >>= 1)
        if (cur + s <= NT - 1 && bndv[cur + s] <= p0) cur += s;
      int nextEnd = bndv[cur + 1];
      float acc[8] = {0.f, 0.f, 0.f, 0.f, 0.f, 0.f, 0.f, 0.f};

      for (int pb = p0; pb < p1; pb += 16) {
        const int m = (p1 - pb < 16) ? (p1 - pb) : 16;
        uint2 mv = make_uint2(0u, 0u);
        if (l16 < m) mv = meta[pb + l16];
        for (int jb = 0; jb < m; jb += 2) {
          // ---- issue both edges' gathers up front (depth-2 MLP) ----
          uint4 av0, av1; float4 r0a, r1a, r0b, r1b; float w0, w1;
          {
            const int j = jb;
            const unsigned pk = (unsigned)__shfl((int)mv.x, j, 16);
            w0 = __uint_as_float(__shfl((int)mv.y, j, 16));
            const int s = (int)(pk & 0xFFFFFu);
            const int t = (int)(pk >> 20);
            av0 = xb4[(size_t)s * 16 + l16];
            r0a = rel4[(size_t)t * 32 + l16 * 2];
            r1a = rel4[(size_t)t * 32 + l16 * 2 + 1];
          }
          {
            int j = jb + 1; if (j >= m) j = m - 1;   // dup of last: harmless
            const unsigned pk = (unsigned)__shfl((int)mv.x, j, 16);
            w1 = __uint_as_float(__shfl((int)mv.y, j, 16));
            const int s = (int)(pk & 0xFFFFFu);
            const int t = (int)(pk >> 20);
            av1 = xb4[(size_t)s * 16 + l16];
            r0b = rel4[(size_t)t * 32 + l16 * 2];
            r1b = rel4[(size_t)t * 32 + l16 * 2 + 1];
          }
          // ---- consume edge jb ----
          {
            const int p = pb + jb;
            while (p >= nextEnd) {
              float* hrow = hsm[cur];
              #pragma unroll
              for (int i = 0; i < 8; ++i) {
                atomicAdd(&hrow[l16 * 8 + i], acc[i]);
                acc[i] = 0.f;
              }
              ++cur; nextEnd = bndv[cur + 1];
            }
            acc[0] += w0 * (bflo(av0.x) - r0a.x);
            acc[1] += w0 * (bfhi(av0.x) - r0a.y);
            acc[2] += w0 * (bflo(av0.y) - r0a.z);
            acc[3] += w0 * (bfhi(av0.y) - r0a.w);
            acc[4] += w0 * (bflo(av0.z) - r1a.x);
            acc[5] += w0 * (bfhi(av0.z) - r1a.y);
            acc[6] += w0 * (bflo(av0.w) - r1a.z);
            acc[7] += w0 * (bfhi(av0.w) - r1a.w);
          }
          // ---- consume edge jb+1 (if real) ----
          if (jb + 1 < m) {
            const int p = pb + jb + 1;
            while (p >= nextEnd) {
              float* hrow = hsm[cur];
              #pragma unroll
              for (int i = 0; i < 8; ++i) {
                atomicAdd(&hrow[l16 * 8 + i], acc[i]);
                acc[i] = 0.f;
              }
              ++cur; nextEnd = bndv[cur + 1];
            }
            acc[0] += w1 * (bflo(av1.x) - r0b.x);
            acc[1] += w1 * (bfhi(av1.x) - r0b.y);
            acc[2] += w1 * (bflo(av1.y) - r0b.z);
            acc[3] += w1 * (bfhi(av1.y) - r0b.w);
            acc[4] += w1 * (bflo(av1.z) - r1b.x);
            acc[5] += w1 * (bfhi(av1.z) - r1b.y);
            acc[6] += w1 * (bflo(av1.w) - r1b.z);
            acc[7] += w1 * (bfhi(av1.w) - r1b.w);
          }
        }
      }
      // final flush
      {
        float* hrow = hsm[cur];
        #pragma unroll
        for (int i = 0; i < 8; ++i)
          atomicAdd(&hrow[l16 * 8 + i], acc[i]);
      }
    }
  } else if (hg) {
    for (int idx = tid; idx < NT * 32; idx += 256) {
      const int rr = idx >> 5, cc = (idx & 31) * 4;
      const int n = g0 + rr;
      float4 v = make_float4(0.f, 0.f, 0.f, 0.f);
      if (n < nN) v = *(const float4*)(hg + (size_t)n * D + cc);
      *(float4*)&hsm[rr][cc] = v;
    }
  }
  __syncthreads();

  // ---- GEMM phase: wave w = (row-half w>>1, col-half w&1) -------------
  const int w = tid >> 6, lane = tid & 63;
  const int q = lane >> 4, r = lane & 15;
  const int rowbase = (w >> 1) * 16;
  const int ch = w & 1;
  const int lr = rowbase + r;
  int grow = g0 + lr; if (grow >= nN) grow = nN - 1;

  f32x4 acc[4];
  #pragma unroll
  for (int c2 = 0; c2 < 4; ++c2) acc[c2] = (f32x4)0.f;

  #pragma unroll
  for (int kt = 0; kt < 4; ++kt) {
    const bf16x8 xa = *(const bf16x8*)(xb + (size_t)grow * D + kt * 32 + q * 8);
    const float* hp = &hsm[lr][kt * 32 + q * 8];
    const float4 h0 = *(const float4*)hp;
    const float4 h1 = *(const float4*)(hp + 4);
    const float hv[8] = {h0.x, h0.y, h0.z, h0.w, h1.x, h1.y, h1.z, h1.w};
    bf16x8 hi, lo;
    #pragma unroll
    for (int j = 0; j < 8; ++j) {
      const unsigned short hb = f2bf(hv[j]);
      hi[j] = (short)hb;
      lo[j] = (short)f2bf(hv[j] - bf2f(hb));
    }
    #pragma unroll
    for (int c2 = 0; c2 < 4; ++c2) {
      const int ct = ch * 4 + c2;
      const bf16x8 bS = *(const bf16x8*)(Wb + ((0 * 8 + ct) * 4 + kt) * 512 + lane * 8);
      const bf16x8 bF = *(const bf16x8*)(Wb + ((1 * 8 + ct) * 4 + kt) * 512 + lane * 8);
      acc[c2] = __builtin_amdgcn_mfma_f32_16x16x32_bf16(xa, bS, acc[c2], 0, 0, 0);
      acc[c2] = __builtin_amdgcn_mfma_f32_16x16x32_bf16(hi, bF, acc[c2], 0, 0, 0);
      acc[c2] = __builtin_amdgcn_mfma_f32_16x16x32_bf16(lo, bF, acc[c2], 0, 0, 0);
    }
  }

  // direct stores: C/D layout col=ct*16+r, row=rowbase+q*4+reg
  #pragma unroll
  for (int c2 = 0; c2 < 4; ++c2) {
    const int col = ch * 64 + c2 * 16 + r;
    const float bv = bias[col];
    #pragma unroll
    for (int reg = 0; reg < 4; ++reg) {
      const int row = g0 + rowbase + q * 4 + reg;
      if (row < nN) out[(size_t)row * D + col] = acc[c2][reg] + bv;
    }
  }
}

// ---------------------------------------------------------------------------
// Fallbacks (never taken at harness sizes)
// ---------------------------------------------------------------------------
__global__ __launch_bounds__(256) void hzero(float* __restrict__ h, int n4) {
  const int i = blockIdx.x * 256 + threadIdx.x;
  if (i < n4) ((int4*)h)[i] = make_int4(0, 0, 0, 0);
}

__global__ __launch_bounds__(256) void hscatter(
    const uint4* __restrict__ xb4, const float* __restrict__ rel,
    const int* __restrict__ ei, const int* __restrict__ etype,
    const float* __restrict__ ew, float* __restrict__ h, int nE) {
  const int e = blockIdx.x * 16 + ((int)threadIdx.x >> 4);
  if (e >= nE) return;
  const int l = threadIdx.x & 15;
  const int s = ei[e], d = ei[nE + e], t = etype[e];
  const float wv = ew[e];
  const uint4 a = xb4[(size_t)s * 16 + l];
  const float4 r0 = ((const float4*)(rel + (size_t)t * D))[l * 2];
  const float4 r1 = ((const float4*)(rel + (size_t)t * D))[l * 2 + 1];
  float* o = h + (size_t)d * D + l * 8;
  atomicAdd(o + 0, wv * (bflo(a.x) - r0.x));
  atomicAdd(o + 1, wv * (bfhi(a.x) - r0.y));
  atomicAdd(o + 2, wv * (bflo(a.y) - r0.z));
  atomicAdd(o + 3, wv * (bfhi(a.y) - r0.w));
  atomicAdd(o + 4, wv * (bflo(a.z) - r1.x));
  atomicAdd(o + 5, wv * (bfhi(a.z) - r1.y));
  atomicAdd(o + 6, wv * (bflo(a.w) - r1.z));
  atomicAdd(o + 7, wv * (bfhi(a.w) - r1.w));
}

// ultra-safe last resort: fp32 per-edge scatter straight into out
__global__ __launch_bounds__(256) void edge_scatter_f32(
    const float* __restrict__ x, const float* __restrict__ rel,
    const float* __restrict__ Wfwd,
    const int* __restrict__ ei, const int* __restrict__ etype,
    const float* __restrict__ ew, float* __restrict__ out, int nE) {
  __shared__ float msg[2][D];
  const int half = (int)threadIdx.x >> 7;     // 2 edges / block
  const int c = threadIdx.x & 127;
  const int e = blockIdx.x * 2 + half;
  if (e >= nE) return;
  const int s = ei[e], d = ei[nE + e], t = etype[e];
  msg[half][c] = x[(size_t)s * D + c] - rel[(size_t)t * D + c];
  __syncthreads();
  float a = 0.f;
  #pragma unroll 8
  for (int k = 0; k < D; ++k) a += msg[half][k] * Wfwd[c * D + k];
  atomicAdd(&out[(size_t)d * D + c], ew[e] * a);
}

// ---------------------------------------------------------------------------
extern "C" void kernel_launch(void* const* d_in, const int* in_sizes, int n_in,
                              void* d_out, int out_size, void* d_ws, size_t ws_size,
                              hipStream_t stream) {
  const float* x      = (const float*)d_in[0];
  const int*   ei     = (const int*)d_in[1];
  const int*   etype  = (const int*)d_in[2];
  const float* rel    = (const float*)d_in[3];
  const float* ew     = (const float*)d_in[4];
  const float* Wself  = (const float*)d_in[5];
  const float* Wfwd   = (const float*)d_in[6];
  const float* Wrel   = (const float*)d_in[7];
  const float* bias   = (const float*)d_in[8];

  const int nN = in_sizes[0] / D;       // 100000
  const int nE = in_sizes[2];           // 625000
  const int nR = in_sizes[3] / D;       // 200

  float* out     = (float*)d_out;
  float* rel_out = (float*)d_out + (size_t)nN * D;

  // workspace carve-up (256B-aligned)
  char* w = (char*)d_ws;
  size_t off = 0;
  auto carve = [&](size_t bytes) {
    char* p = w + off;
    off = (off + bytes + 255) & ~(size_t)255;
    return p;
  };
  unsigned short* xb  = (unsigned short*)carve((size_t)nN * D * sizeof(unsigned short));
  unsigned short* Wb  = (unsigned short*)carve(2 * 8 * 4 * 512 * sizeof(unsigned short));
  int*   offs = (int*)carve((size_t)nN * sizeof(int));
  uint2* meta = (uint2*)carve((size_t)nE * sizeof(uint2));
  int*   bsum = (int*)carve(1024 * sizeof(int));
  const size_t need = off;

  const int* dst = ei + nE;
  const int nb = (nN + SCAN_B - 1) / SCAN_B;
  const int relBlocks  = (nR + 1) / 2;
  const int zeroBlocks = (nN + 1023) / 1024;
  const int xbBlocks   = (int)(((size_t)nN * D + 2047) / 2048);
  const int histBlocks = (nE + 1023) / 1024;
  const int aggBlocks  = (nN + NT - 1) / NT;

  const bool csr_ok = (need <= ws_size) && (nb <= 1024) &&
                      (nN < (1 << 20)) && (nR <= 4096);
  const size_t hBytes = (size_t)nN * D * sizeof(float);
  const bool h_ok = ((size_t)nN * D * sizeof(unsigned short) + 256 + hBytes) <= ws_size;

  // Wb prep + rel_out GEMV + zero offs + xb=bf16(x)  (one dispatch)
  prep_kernel<<<16 + relBlocks + zeroBlocks + xbBlocks, 256, 0, stream>>>(
      Wself, Wfwd, rel, Wrel, x, xb, Wb, rel_out, offs, nR, nN,
      relBlocks, zeroBlocks, nN * D);

  if (csr_ok) {
    hist_kernel<<<histBlocks, 256, 0, stream>>>(dst, offs, nE);
    scan_pass1<<<nb, SCAN_B, 0, stream>>>(offs, bsum, nN);
    scan_pass2<<<1, 1024, 0, stream>>>(bsum, nb);
    scan_pass3<<<nb, SCAN_B, 0, stream>>>(offs, bsum, nN);
    fill_kernel<<<(nE + 255) / 256, 256, 0, stream>>>(ei, dst, etype, ew, offs, meta, nE);
    fused_ag<<<aggBlocks, 256, 0, stream>>>(
        (const uint4*)xb, (const float4*)rel, meta, offs, Wb, bias, xb, out,
        nN, 0, (const float*)0);
  } else if (h_ok) {
    // h in global via atomics, then the same fused GEMM
    float* h = (float*)(w + (((size_t)nN * D * sizeof(unsigned short) + 255) & ~(size_t)255));
    const int n4 = (nN * D) / 4;
    hzero<<<(n4 + 255) / 256, 256, 0, stream>>>(h, n4);
    hscatter<<<(nE + 15) / 16, 256, 0, stream>>>(
        (const uint4*)xb, rel, ei, etype, ew, h, nE);
    fused_ag<<<aggBlocks, 256, 0, stream>>>(
        (const uint4*)xb, (const float4*)rel, (const uint2*)0, (const int*)0,
        Wb, bias, xb, out, nN, 1, h);
  } else {
    // last resort: fused self-GEMM with h=0 (hg==null -> hsm stays zero),
    // then fp32 per-edge atomic scatter of the message term
    fused_ag<<<aggBlocks, 256, 0, stream>>>(
        (const uint4*)xb, (const float4*)rel, (const uint2*)0, (const int*)0,
        Wb, bias, xb, out, nN, 1, (const float*)0);
    edge_scatter_f32<<<(nE + 1) / 2, 256, 0, stream>>>(
        x, rel, Wfwd, ei, etype, ew, out, nE);
  }
}

// Round 5
// 241.516 us; speedup vs baseline: 1.2473x; 1.2215x over previous
//
#include <hip/hip_runtime.h>

#define D 128
#define SCAN_B 256
#define NT 32            // nodes per fused_ag block
#define HPAD 132         // padded LDS row (floats) — breaks stride-128 bank alias

typedef short bf16x8 __attribute__((ext_vector_type(8)));
typedef float f32x4 __attribute__((ext_vector_type(4)));

static __device__ __forceinline__ unsigned short f2bf(float f) {
  union { float f; unsigned u; } v; v.f = f;
  return (unsigned short)((v.u + 0x7FFF + ((v.u >> 16) & 1)) >> 16);   // RNE
}
static __device__ __forceinline__ float bf2f(unsigned short h) {
  union { unsigned u; float f; } v; v.u = ((unsigned)h) << 16;
  return v.f;
}
static __device__ __forceinline__ float bflo(unsigned u) {
  union { unsigned u; float f; } v; v.u = u << 16; return v.f;
}
static __device__ __forceinline__ float bfhi(unsigned u) {
  union { unsigned u; float f; } v; v.u = u & 0xFFFF0000u; return v.f;
}

// ---------------------------------------------------------------------------
// prep_kernel: blocks [0,16)            : Wself/Wfwd -> bf16 MFMA-B-swizzled Wb
//              [16, +relBlocks)         : rel_out = rel @ Wr^T (2 rows/block)
//              [.., +zeroBlocks)        : zero offs (int4 stores)
//              rest                     : xb = bf16(x)   (no deps on above)
// ---------------------------------------------------------------------------
__global__ __launch_bounds__(256) void prep_kernel(
    const float* __restrict__ Wself, const float* __restrict__ Wfwd,
    const float* __restrict__ rel, const float* __restrict__ Wr,
    const float* __restrict__ x, unsigned short* __restrict__ xb,
    unsigned short* __restrict__ Wb, float* __restrict__ rel_out,
    int* __restrict__ offs, int nR, int nN, int relBlocks, int zeroBlocks,
    int xbElems) {
  const int tid = threadIdx.x;
  const int bid = (int)blockIdx.x;
  if (bid < 16) {
    // Wb[frag*512 + lane*8 + j]: frag=((mat*8+ct)*4+kt); lane(q=lane>>4,r=lane&15)
    // holds W[ct*16+r][kt*32+q*8+j].  mat0=Wself, mat1=Wfwd.
    const int g = bid * 256 + tid;     // 0..4095
    const int frag = g >> 6, lane = g & 63;
    const int mat = frag >> 5, ct = (frag >> 2) & 7, kt = frag & 3;
    const int q = lane >> 4, r = lane & 15;
    const float* W = mat ? Wfwd : Wself;
    const float* src = W + (ct * 16 + r) * D + kt * 32 + q * 8;
    unsigned short* dstp = Wb + frag * 512 + lane * 8;
    #pragma unroll
    for (int j = 0; j < 8; ++j) dstp[j] = f2bf(src[j]);
  } else if (bid < 16 + relBlocks) {
    __shared__ float row[2][D];
    const int half = tid >> 7;                 // 0/1: which rel row
    const int c = tid & 127;
    const int rr = (bid - 16) * 2 + half;
    const int r2 = (rr < nR) ? rr : nR - 1;
    row[half][c] = rel[r2 * D + c];
    __syncthreads();
    const float4* xr4 = (const float4*)row[half];
    const float4* Wr4 = (const float4*)(Wr + c * D);
    float ar = 0.f;
    #pragma unroll 8
    for (int k4 = 0; k4 < 32; ++k4) {
      const float4 xv = xr4[k4];
      const float4 wr = Wr4[k4];
      ar += xv.x * wr.x + xv.y * wr.y + xv.z * wr.z + xv.w * wr.w;
    }
    if (rr < nR) rel_out[rr * D + c] = ar;
  } else if (bid < 16 + relBlocks + zeroBlocks) {
    const int i = (bid - 16 - relBlocks) * 256 + tid;  // int4 index
    const int e0 = i * 4;
    if (e0 < nN) {
      if (e0 + 3 < nN) ((int4*)offs)[i] = make_int4(0, 0, 0, 0);
      else { for (int k = e0; k < nN; ++k) offs[k] = 0; }
    }
  } else {
    const int i = ((bid - 16 - relBlocks - zeroBlocks) * 256 + tid) * 8;
    if (i + 7 < xbElems) {
      const float4 u0 = *(const float4*)(x + i);
      const float4 u1 = *(const float4*)(x + i + 4);
      const unsigned p0 = (unsigned)f2bf(u0.x) | ((unsigned)f2bf(u0.y) << 16);
      const unsigned p1 = (unsigned)f2bf(u0.z) | ((unsigned)f2bf(u0.w) << 16);
      const unsigned p2 = (unsigned)f2bf(u1.x) | ((unsigned)f2bf(u1.y) << 16);
      const unsigned p3 = (unsigned)f2bf(u1.z) | ((unsigned)f2bf(u1.w) << 16);
      *(int4*)(xb + i) = make_int4((int)p0, (int)p1, (int)p2, (int)p3);
    } else {
      for (int k = i; k < xbElems; ++k) xb[k] = f2bf(x[k]);
    }
  }
}

// ---------------------------------------------------------------------------
// hist_kernel: dst histogram into offs (offs zeroed by prep)
// ---------------------------------------------------------------------------
__global__ __launch_bounds__(256) void hist_kernel(
    const int* __restrict__ dst, int* __restrict__ offs, int nE) {
  const int i0 = ((int)blockIdx.x * 256 + (int)threadIdx.x) * 4;
  if (i0 + 3 < nE) {
    const int4 d4 = *(const int4*)(dst + i0);
    atomicAdd(&offs[d4.x], 1); atomicAdd(&offs[d4.y], 1);
    atomicAdd(&offs[d4.z], 1); atomicAdd(&offs[d4.w], 1);
  } else {
    for (int e = i0; e < nE && e < i0 + 4; ++e) atomicAdd(&offs[dst[e]], 1);
  }
}

// ---------------------------------------------------------------------------
// scan: pass1 computes per-block sums; pass3 recomputes its block offset from
// bsum directly (pass2 folded in — one fewer dispatch).
// ---------------------------------------------------------------------------
__global__ __launch_bounds__(SCAN_B) void scan_pass1(
    const int* __restrict__ deg, int* __restrict__ bsum, int n) {
  __shared__ int sd[SCAN_B];
  const int i = blockIdx.x * SCAN_B + threadIdx.x;
  sd[threadIdx.x] = (i < n) ? deg[i] : 0;
  __syncthreads();
  for (int s = SCAN_B / 2; s > 0; s >>= 1) {
    if (threadIdx.x < s) sd[threadIdx.x] += sd[threadIdx.x + s];
    __syncthreads();
  }
  if (threadIdx.x == 0) bsum[blockIdx.x] = sd[0];
}

__global__ __launch_bounds__(SCAN_B) void scan_pass3(
    int* __restrict__ deg_offs, const int* __restrict__ bsum, int n) {
  __shared__ int sd[SCAN_B];
  __shared__ int boffs;
  const int t = threadIdx.x;
  // block offset = sum of bsum[0 .. blockIdx.x)
  int partial = 0;
  for (int j = t; j < (int)blockIdx.x; j += SCAN_B) partial += bsum[j];
  sd[t] = partial;
  __syncthreads();
  for (int s = SCAN_B / 2; s > 0; s >>= 1) {
    if (t < s) sd[t] += sd[t + s];
    __syncthreads();
  }
  if (t == 0) boffs = sd[0];
  __syncthreads();
  const int i = blockIdx.x * SCAN_B + t;
  const int v = (i < n) ? deg_offs[i] : 0;
  sd[t] = v;
  __syncthreads();
  for (int off = 1; off < SCAN_B; off <<= 1) {
    const int add = (t >= off) ? sd[t - off] : 0;
    __syncthreads();
    sd[t] += add;
    __syncthreads();
  }
  if (i < n) deg_offs[i] = sd[t] - v + boffs;   // exclusive global
}

// ---------------------------------------------------------------------------
// fill: CSR-ordered PACKED metadata. meta[p] = {src | et<<20, bits(ew)}.
// After this, offs[n] == end of bucket n (cursor advanced to end).
// ---------------------------------------------------------------------------
__global__ void fill_kernel(const int* __restrict__ src, const int* __restrict__ dstv,
                            const int* __restrict__ et, const float* __restrict__ ew,
                            int* __restrict__ cursor, uint2* __restrict__ meta, int nE) {
  const int e = blockIdx.x * blockDim.x + threadIdx.x;
  if (e < nE) {
    const int p = atomicAdd(&cursor[dstv[e]], 1);
    meta[p] = make_uint2((unsigned)src[e] | ((unsigned)et[e] << 20),
                         __float_as_uint(ew[e]));
  }
}

// ---------------------------------------------------------------------------
// fused_ag v4: aggregate-then-project, h never touches HBM.
//  Agg: 32 LANES per node (8 groups/block, NT=32 nodes over 4 rounds);
//  group OWNS its node (straight-line inner loop, no boundary branches, no
//  LDS atomics — v2/v3's balanced-walk poisoned codegen: VGPR 36, serial
//  gathers, 120us). Per edge per lane: uint2 xb + float4 rel (6 VGPR) —
//  PAIR-processed (2 edges per iter, branch-free) for depth-2 MLP.
//  (256,8): VGPR<=64 -> 8 blocks/CU (17.4KB LDS) = up to 32 waves/CU.
//  GEMM: 4 waves = (row-half, col-half); acc = x@Ws + hi@Wf + lo@Wf.
// ---------------------------------------------------------------------------
__global__ __launch_bounds__(256, 8) void fused_ag(
    const unsigned short* __restrict__ xb, const float4* __restrict__ rel4,
    const uint2* __restrict__ meta, const int* __restrict__ offs,
    const unsigned short* __restrict__ Wb, const float* __restrict__ bias,
    float* __restrict__ out,
    int nN, int useGlobalH, const float* __restrict__ hg) {
  __shared__ float hsm[NT][HPAD];          // ~16.9 KB
  __shared__ int bndv[NT + 1];
  const int tid = threadIdx.x;
  const int g0 = blockIdx.x * NT;
  const uint2* xb2 = (const uint2*)xb;

  if (!useGlobalH) {
    if (tid <= NT) {
      int v;
      if (tid == 0) v = (g0 == 0) ? 0 : offs[g0 - 1];
      else { int idx = g0 + tid - 1; if (idx > nN - 1) idx = nN - 1; v = offs[idx]; }
      bndv[tid] = v;
    }
    __syncthreads();

    const int g = tid >> 5;          // group 0..7
    const int l32 = tid & 31;
    #pragma unroll
    for (int r = 0; r < NT / 8; ++r) {
      const int nl = r * 8 + g;
      const int n = g0 + nl;
      if (n < nN) {
        float a0 = 0.f, a1 = 0.f, a2 = 0.f, a3 = 0.f;
        const int start = bndv[nl], end = bndv[nl + 1];
        for (int base = start; base < end; base += 32) {
          const int m = (end - base < 32) ? (end - base) : 32;
          uint2 mv = make_uint2(0u, 0u);
          if (l32 < m) mv = meta[base + l32];
          int jb = 0;
          for (; jb + 2 <= m; jb += 2) {
            // two edges, branch-free: issue all 4 gathers, then consume
            const unsigned pkA = (unsigned)__shfl((int)mv.x, jb, 32);
            const float wA = __uint_as_float(__shfl((int)mv.y, jb, 32));
            const unsigned pkB = (unsigned)__shfl((int)mv.x, jb + 1, 32);
            const float wB = __uint_as_float(__shfl((int)mv.y, jb + 1, 32));
            const uint2 avA = xb2[(size_t)(pkA & 0xFFFFFu) * 32 + l32];
            const float4 rA = rel4[(size_t)(pkA >> 20) * 32 + l32];
            const uint2 avB = xb2[(size_t)(pkB & 0xFFFFFu) * 32 + l32];
            const float4 rB = rel4[(size_t)(pkB >> 20) * 32 + l32];
            a0 += wA * (bflo(avA.x) - rA.x);
            a1 += wA * (bfhi(avA.x) - rA.y);
            a2 += wA * (bflo(avA.y) - rA.z);
            a3 += wA * (bfhi(avA.y) - rA.w);
            a0 += wB * (bflo(avB.x) - rB.x);
            a1 += wB * (bfhi(avB.x) - rB.y);
            a2 += wB * (bflo(avB.y) - rB.z);
            a3 += wB * (bfhi(avB.y) - rB.w);
          }
          if (jb < m) {
            const unsigned pk = (unsigned)__shfl((int)mv.x, jb, 32);
            const float wv = __uint_as_float(__shfl((int)mv.y, jb, 32));
            const uint2 av = xb2[(size_t)(pk & 0xFFFFFu) * 32 + l32];
            const float4 rv = rel4[(size_t)(pk >> 20) * 32 + l32];
            a0 += wv * (bflo(av.x) - rv.x);
            a1 += wv * (bfhi(av.x) - rv.y);
            a2 += wv * (bflo(av.y) - rv.z);
            a3 += wv * (bfhi(av.y) - rv.w);
          }
        }
        *(float4*)&hsm[nl][l32 * 4] = make_float4(a0, a1, a2, a3);
      }
    }
  } else {
    for (int idx = tid; idx < NT * 32; idx += 256) {
      const int rr = idx >> 5, cc = (idx & 31) * 4;
      const int n = g0 + rr;
      float4 v = make_float4(0.f, 0.f, 0.f, 0.f);
      if (n < nN && hg) v = *(const float4*)(hg + (size_t)n * D + cc);
      *(float4*)&hsm[rr][cc] = v;
    }
  }
  __syncthreads();

  // ---- GEMM phase: wave w = (row-half w>>1, col-half w&1) -------------
  const int w = tid >> 6, lane = tid & 63;
  const int q = lane >> 4, r = lane & 15;
  const int rowbase = (w >> 1) * 16;
  const int ch = w & 1;
  const int lr = rowbase + r;
  int grow = g0 + lr; if (grow >= nN) grow = nN - 1;

  f32x4 acc[4];
  #pragma unroll
  for (int c2 = 0; c2 < 4; ++c2) acc[c2] = (f32x4)0.f;

  #pragma unroll
  for (int kt = 0; kt < 4; ++kt) {
    const bf16x8 xa = *(const bf16x8*)(xb + (size_t)grow * D + kt * 32 + q * 8);
    const float* hp = &hsm[lr][kt * 32 + q * 8];
    const float4 h0 = *(const float4*)hp;
    const float4 h1 = *(const float4*)(hp + 4);
    const float hv[8] = {h0.x, h0.y, h0.z, h0.w, h1.x, h1.y, h1.z, h1.w};
    bf16x8 hi, lo;
    #pragma unroll
    for (int j = 0; j < 8; ++j) {
      const unsigned short hb = f2bf(hv[j]);
      hi[j] = (short)hb;
      lo[j] = (short)f2bf(hv[j] - bf2f(hb));
    }
    #pragma unroll
    for (int c2 = 0; c2 < 4; ++c2) {
      const int ct = ch * 4 + c2;
      const bf16x8 bS = *(const bf16x8*)(Wb + ((0 * 8 + ct) * 4 + kt) * 512 + lane * 8);
      const bf16x8 bF = *(const bf16x8*)(Wb + ((1 * 8 + ct) * 4 + kt) * 512 + lane * 8);
      acc[c2] = __builtin_amdgcn_mfma_f32_16x16x32_bf16(xa, bS, acc[c2], 0, 0, 0);
      acc[c2] = __builtin_amdgcn_mfma_f32_16x16x32_bf16(hi, bF, acc[c2], 0, 0, 0);
      acc[c2] = __builtin_amdgcn_mfma_f32_16x16x32_bf16(lo, bF, acc[c2], 0, 0, 0);
    }
  }

  // direct stores: C/D layout col=ct*16+r, row=rowbase+q*4+reg
  #pragma unroll
  for (int c2 = 0; c2 < 4; ++c2) {
    const int col = ch * 64 + c2 * 16 + r;
    const float bv = bias[col];
    #pragma unroll
    for (int reg = 0; reg < 4; ++reg) {
      const int row = g0 + rowbase + q * 4 + reg;
      if (row < nN) out[(size_t)row * D + col] = acc[c2][reg] + bv;
    }
  }
}

// ---------------------------------------------------------------------------
// Fallbacks (never taken at harness sizes)
// ---------------------------------------------------------------------------
__global__ __launch_bounds__(256) void hzero(float* __restrict__ h, int n4) {
  const int i = blockIdx.x * 256 + threadIdx.x;
  if (i < n4) ((int4*)h)[i] = make_int4(0, 0, 0, 0);
}

__global__ __launch_bounds__(256) void hscatter(
    const uint4* __restrict__ xb4, const float* __restrict__ rel,
    const int* __restrict__ ei, const int* __restrict__ etype,
    const float* __restrict__ ew, float* __restrict__ h, int nE) {
  const int e = blockIdx.x * 16 + ((int)threadIdx.x >> 4);
  if (e >= nE) return;
  const int l = threadIdx.x & 15;
  const int s = ei[e], d = ei[nE + e], t = etype[e];
  const float wv = ew[e];
  const uint4 a = xb4[(size_t)s * 16 + l];
  const float4 r0 = ((const float4*)(rel + (size_t)t * D))[l * 2];
  const float4 r1 = ((const float4*)(rel + (size_t)t * D))[l * 2 + 1];
  float* o = h + (size_t)d * D + l * 8;
  atomicAdd(o + 0, wv * (bflo(a.x) - r0.x));
  atomicAdd(o + 1, wv * (bfhi(a.x) - r0.y));
  atomicAdd(o + 2, wv * (bflo(a.y) - r0.z));
  atomicAdd(o + 3, wv * (bfhi(a.y) - r0.w));
  atomicAdd(o + 4, wv * (bflo(a.z) - r1.x));
  atomicAdd(o + 5, wv * (bfhi(a.z) - r1.y));
  atomicAdd(o + 6, wv * (bflo(a.w) - r1.z));
  atomicAdd(o + 7, wv * (bfhi(a.w) - r1.w));
}

// ultra-safe last resort: fp32 per-edge scatter straight into out
__global__ __launch_bounds__(256) void edge_scatter_f32(
    const float* __restrict__ x, const float* __restrict__ rel,
    const float* __restrict__ Wfwd,
    const int* __restrict__ ei, const int* __restrict__ etype,
    const float* __restrict__ ew, float* __restrict__ out, int nE) {
  __shared__ float msg[2][D];
  const int half = (int)threadIdx.x >> 7;     // 2 edges / block
  const int c = threadIdx.x & 127;
  const int e = blockIdx.x * 2 + half;
  if (e >= nE) return;
  const int s = ei[e], d = ei[nE + e], t = etype[e];
  msg[half][c] = x[(size_t)s * D + c] - rel[(size_t)t * D + c];
  __syncthreads();
  float a = 0.f;
  #pragma unroll 8
  for (int k = 0; k < D; ++k) a += msg[half][k] * Wfwd[c * D + k];
  atomicAdd(&out[(size_t)d * D + c], ew[e] * a);
}

// ---------------------------------------------------------------------------
extern "C" void kernel_launch(void* const* d_in, const int* in_sizes, int n_in,
                              void* d_out, int out_size, void* d_ws, size_t ws_size,
                              hipStream_t stream) {
  const float* x      = (const float*)d_in[0];
  const int*   ei     = (const int*)d_in[1];
  const int*   etype  = (const int*)d_in[2];
  const float* rel    = (const float*)d_in[3];
  const float* ew     = (const float*)d_in[4];
  const float* Wself  = (const float*)d_in[5];
  const float* Wfwd   = (const float*)d_in[6];
  const float* Wrel   = (const float*)d_in[7];
  const float* bias   = (const float*)d_in[8];

  const int nN = in_sizes[0] / D;       // 100000
  const int nE = in_sizes[2];           // 625000
  const int nR = in_sizes[3] / D;       // 200

  float* out     = (float*)d_out;
  float* rel_out = (float*)d_out + (size_t)nN * D;

  // workspace carve-up (256B-aligned)
  char* w = (char*)d_ws;
  size_t off = 0;
  auto carve = [&](size_t bytes) {
    char* p = w + off;
    off = (off + bytes + 255) & ~(size_t)255;
    return p;
  };
  unsigned short* xb  = (unsigned short*)carve((size_t)nN * D * sizeof(unsigned short));
  unsigned short* Wb  = (unsigned short*)carve(2 * 8 * 4 * 512 * sizeof(unsigned short));
  int*   offs = (int*)carve((size_t)nN * sizeof(int));
  uint2* meta = (uint2*)carve((size_t)nE * sizeof(uint2));
  int*   bsum = (int*)carve(1024 * sizeof(int));
  const size_t need = off;

  const int* dst = ei + nE;
  const int nb = (nN + SCAN_B - 1) / SCAN_B;
  const int relBlocks  = (nR + 1) / 2;
  const int zeroBlocks = (nN + 1023) / 1024;
  const int xbBlocks   = (int)(((size_t)nN * D + 2047) / 2048);
  const int histBlocks = (nE + 1023) / 1024;
  const int aggBlocks  = (nN + NT - 1) / NT;

  const bool csr_ok = (need <= ws_size) && (nb <= 1024) &&
                      (nN < (1 << 20)) && (nR <= 4096);
  const size_t hBytes = (size_t)nN * D * sizeof(float);
  const bool h_ok = ((size_t)nN * D * sizeof(unsigned short) + 256 + hBytes) <= ws_size;

  // Wb prep + rel_out GEMV + zero offs + xb=bf16(x)  (one dispatch)
  prep_kernel<<<16 + relBlocks + zeroBlocks + xbBlocks, 256, 0, stream>>>(
      Wself, Wfwd, rel, Wrel, x, xb, Wb, rel_out, offs, nR, nN,
      relBlocks, zeroBlocks, nN * D);

  if (csr_ok) {
    hist_kernel<<<histBlocks, 256, 0, stream>>>(dst, offs, nE);
    scan_pass1<<<nb, SCAN_B, 0, stream>>>(offs, bsum, nN);
    scan_pass3<<<nb, SCAN_B, 0, stream>>>(offs, bsum, nN);
    fill_kernel<<<(nE + 255) / 256, 256, 0, stream>>>(ei, dst, etype, ew, offs, meta, nE);
    fused_ag<<<aggBlocks, 256, 0, stream>>>(
        xb, (const float4*)rel, meta, offs, Wb, bias, out,
        nN, 0, (const float*)0);
  } else if (h_ok) {
    // h in global via atomics, then the same fused GEMM
    float* h = (float*)(w + (((size_t)nN * D * sizeof(unsigned short) + 255) & ~(size_t)255));
    const int n4 = (nN * D) / 4;
    hzero<<<(n4 + 255) / 256, 256, 0, stream>>>(h, n4);
    hscatter<<<(nE + 15) / 16, 256, 0, stream>>>(
        (const uint4*)xb, rel, ei, etype, ew, h, nE);
    fused_ag<<<aggBlocks, 256, 0, stream>>>(
        xb, (const float4*)rel, (const uint2*)0, (const int*)0,
        Wb, bias, out, nN, 1, h);
  } else {
    // last resort: fused self-GEMM with h=0 (hg==null -> hsm zero-filled),
    // then fp32 per-edge atomic scatter of the message term
    fused_ag<<<aggBlocks, 256, 0, stream>>>(
        xb, (const float4*)rel, (const uint2*)0, (const int*)0,
        Wb, bias, out, nN, 1, (const float*)0);
    edge_scatter_f32<<<(nE + 1) / 2, 256, 0, stream>>>(
        x, rel, Wfwd, ei, etype, ew, out, nE);
  }
}